// Round 8
// baseline (628.859 us; speedup 1.0000x reference)
//
#include <hip/hip_runtime.h>

// LSTM (B=2048, T=1024, I=8, H=64) + sigmoid(FC), bf16 MFMA.
// Round 8: TWO recurrence instances per wave (groups A=rows 0..3, B=rows 4..7).
// Per barrier interval each wave issues MFMA_A + MFMA_B (24, independent) and
// act_A + act_B -> matrix-pipe and transcendental work overlap by construction
// inside one wave; ONE barrier advances both groups one timestep.
// 256 blocks x 256 thr = 1 block/CU. Weights (A-frags) shared by both groups:
// wave wv owns gate-strided M-tiles {4g+wv} so acc[g] = gate-type g of
// jh = 16wv+4g4+rsel; thread activates one element per group (cndmask tree).
// K=96 packed [x(8)|bias|0.. | h(64)]; x staged as full 32-wide K-rows
// (const channels prefilled once) -> fx is a single b128 read, no selects.
// h double-buffered, HP=72 >= 64 (fixes r5's row-overlap race).

namespace {
constexpr int T_LEN = 1024;
constexpr int R     = 8;     // rows/block: group A = 0..3, group B = 4..7
constexpr int TS    = 32;    // timesteps per staged x chunk
constexpr int NCH   = T_LEN / TS;
constexpr int HP    = 72;    // h row stride (shorts): 36 dw, 2-way banks (free)

typedef __attribute__((ext_vector_type(8))) short  short8v;
typedef __attribute__((ext_vector_type(4))) float  float4v;
typedef unsigned short u16;
typedef unsigned int   u32;
typedef unsigned long long u64;

__device__ __forceinline__ float fsig(float x) {
  return __builtin_amdgcn_rcpf(1.f + __expf(-x));
}
__device__ __forceinline__ float ftanh(float x) {
  return 1.f - 2.f * __builtin_amdgcn_rcpf(__expf(2.f * x) + 1.f);
}
__device__ __forceinline__ u16 f2bf(float f) {  // RNE
  u32 u = __float_as_uint(f);
  u32 r = ((u >> 16) & 1u) + 0x7fffu;
  return (u16)((u + r) >> 16);
}

__global__ __launch_bounds__(256, 1) void lstm_dual(
    const float* __restrict__ x,     // [B, T, 8]
    const float* __restrict__ W_ih,  // [256, 8]
    const float* __restrict__ W_hh,  // [256, 64]
    const float* __restrict__ b_ih,  // [256]
    const float* __restrict__ b_hh,  // [256]
    const float* __restrict__ fc_w,  // [64]
    const float* __restrict__ fc_b,  // [1]
    float* __restrict__ out) {       // [B]
  __shared__ __align__(16) u16   x_lds[2][TS][R][32];  // 32 KB, full K-rows
  __shared__ __align__(16) u16   h_lds[2][R][HP];      // 2.25 KB
  __shared__ __align__(16) float hf[R][64];            // final h (fp32)

  const int tid  = threadIdx.x;
  const int lane = tid & 63;
  const int wv   = tid >> 6;        // wave 0..3
  const int g4   = lane >> 4;       // MFMA k-quad / C row-quad
  const int nib  = lane & 15;       // MFMA m/n coord
  const int rowA = nib & 3;         // group A batch row (cols duplicate x4)
  const int rowB = 4 + rowA;        // group B batch row
  const int rsel = nib >> 2;        // which acc reg this thread activates
  const int jh   = 16 * wv + 4 * g4 + rsel;   // owned h index (both groups)
  const int bBase = blockIdx.x * R;

  // ---- static A fragments (shared by both groups): wave wv owns tiles
  // q = 4g+wv (g = gate type i,f,g,o). A[m=16q+nib][k=8*g4+j].
  // a0: k=0..31 = [W_ih(8)|bias|0...], a1 = W_hh[:,0:32], a2 = W_hh[:,32:64].
  short8v a0[4], a1[4], a2[4];
  for (int g = 0; g < 4; ++g) {
    const int n = 16 * (4 * g + wv) + nib;  // gate row
    short8v f0, f1, f2;
    for (int j = 0; j < 8; ++j) {
      const int k = 8 * g4 + j;
      float v0 = 0.f;
      if (k < 8) v0 = W_ih[n * 8 + k];
      else if (k == 8) v0 = b_ih[n] + b_hh[n];
      f0[j] = (short)f2bf(v0);
      f1[j] = (short)f2bf(W_hh[n * 64 + k]);
      f2[j] = (short)f2bf(W_hh[n * 64 + 32 + k]);
    }
    a0[g] = f0; a1[g] = f1; a2[g] = f2;
  }

  // ---- LDS init: h0 = 0 (both bufs); x constant channels once per buf ----
  for (int i = tid; i < 2 * R * HP; i += 256) ((u16*)h_lds)[i] = 0;
  for (int s = tid; s < 2 * TS * R; s += 256) {  // 2 iters
    const int buf = s >> 8, rem = s & 255, tt = rem >> 3, rr = rem & 7;
    u16* p = &x_lds[buf][tt][rr][0];
    p[8] = 0x3f80;  // bias channel = 1.0
    for (int chn = 9; chn < 32; ++chn) p[chn] = 0;
  }

  // ---- x staging: 2 float4/thread/chunk, double-buffered ----
  float4v xr[2];
  auto stage_load = [&](int chunk) {
#pragma unroll
    for (int p = 0; p < 2; ++p) {
      const int fi = tid + 256 * p;              // float4 idx 0..511
      const int sr = fi >> 6, m4 = fi & 63;      // row, float4-in-row-chunk
      xr[p] = *(const float4v*)&x[(size_t)(bBase + sr) * (T_LEN * 8) +
                                  (size_t)chunk * (TS * 8) + m4 * 4];
    }
  };
  auto stage_write = [&](int buf) {
#pragma unroll
    for (int p = 0; p < 2; ++p) {
      const int fi = tid + 256 * p;
      const int sr = fi >> 6, m4 = fi & 63;
      const int tt = m4 >> 1, c4 = (m4 & 1) * 4;
      union { u64 u; u16 s[4]; } pk;
      pk.s[0] = f2bf(xr[p][0]); pk.s[1] = f2bf(xr[p][1]);
      pk.s[2] = f2bf(xr[p][2]); pk.s[3] = f2bf(xr[p][3]);
      *(u64*)&x_lds[buf][tt][sr][c4] = pk.u;
    }
  };

  stage_load(0);
  stage_write(0);
  __syncthreads();

  const bool sel1 = (rsel & 1) != 0;
  const bool sel2 = (rsel & 2) != 0;
  float cA = 0.f, cB = 0.f;

  for (int ch = 0; ch < NCH; ++ch) {
    const int buf = ch & 1;
    const bool more = (ch + 1 < NCH);
#pragma unroll 2
    for (int tt = 0; tt < TS; ++tt) {
      const int t = ch * TS + tt;
      const int hb = t & 1;
      if (tt == 0 && more) stage_load(ch + 1);  // regs; drains at stage_write

      // ---- B fragments: both groups (6 b128 reads) ----
      const short8v fxA  = *(const short8v*)&x_lds[buf][tt][rowA][8 * g4];
      const short8v fxB  = *(const short8v*)&x_lds[buf][tt][rowB][8 * g4];
      const short8v fhA0 = *(const short8v*)&h_lds[hb][rowA][8 * g4];
      const short8v fhA1 = *(const short8v*)&h_lds[hb][rowA][32 + 8 * g4];
      const short8v fhB0 = *(const short8v*)&h_lds[hb][rowB][8 * g4];
      const short8v fhB1 = *(const short8v*)&h_lds[hb][rowB][32 + 8 * g4];

      // ---- 24 MFMAs: two independent 12-MFMA sets, grouped by K-level ----
      float4v accA[4], accB[4];
#pragma unroll
      for (int g = 0; g < 4; ++g) {
        accA[g] = __builtin_amdgcn_mfma_f32_16x16x32_bf16(
            a0[g], fxA, (float4v){0.f, 0.f, 0.f, 0.f}, 0, 0, 0);
        accB[g] = __builtin_amdgcn_mfma_f32_16x16x32_bf16(
            a0[g], fxB, (float4v){0.f, 0.f, 0.f, 0.f}, 0, 0, 0);
      }
#pragma unroll
      for (int g = 0; g < 4; ++g) {
        accA[g] = __builtin_amdgcn_mfma_f32_16x16x32_bf16(a1[g], fhA0, accA[g], 0, 0, 0);
        accB[g] = __builtin_amdgcn_mfma_f32_16x16x32_bf16(a1[g], fhB0, accB[g], 0, 0, 0);
      }
#pragma unroll
      for (int g = 0; g < 4; ++g) {
        accA[g] = __builtin_amdgcn_mfma_f32_16x16x32_bf16(a2[g], fhA1, accA[g], 0, 0, 0);
        accB[g] = __builtin_amdgcn_mfma_f32_16x16x32_bf16(a2[g], fhB1, accB[g], 0, 0, 0);
      }

      // ---- activations: one element per group per thread ----
      float gvA[4], gvB[4];
#pragma unroll
      for (int g = 0; g < 4; ++g) {
        const float a01 = sel1 ? accA[g][1] : accA[g][0];
        const float a23 = sel1 ? accA[g][3] : accA[g][2];
        gvA[g] = sel2 ? a23 : a01;
        const float b01 = sel1 ? accB[g][1] : accB[g][0];
        const float b23 = sel1 ? accB[g][3] : accB[g][2];
        gvB[g] = sel2 ? b23 : b01;
      }
      const float iA = fsig(gvA[0]), fA = fsig(gvA[1]);
      const float gA = ftanh(gvA[2]), oA = fsig(gvA[3]);
      cA = fA * cA + iA * gA;
      const float hA = oA * ftanh(cA);
      const float iB = fsig(gvB[0]), fB = fsig(gvB[1]);
      const float gB = ftanh(gvB[2]), oB = fsig(gvB[3]);
      cB = fB * cB + iB * gB;
      const float hB = oB * ftanh(cB);

      h_lds[hb ^ 1][rowA][jh] = f2bf(hA);
      h_lds[hb ^ 1][rowB][jh] = f2bf(hB);
      if (t == T_LEN - 1) {
        hf[rowA][jh] = hA;
        hf[rowB][jh] = hB;
      }
      if (tt == TS - 1 && more) stage_write(buf ^ 1);
      __syncthreads();  // one barrier advances BOTH groups one step
    }
  }

  // ---- epilogue: out[b] = sigmoid(hT . fc_w + fc_b) ----
  if (tid < R) {
    float a = fc_b[0];
#pragma unroll
    for (int k = 0; k < 64; ++k) a += hf[tid][k] * fc_w[k];
    out[bBase + tid] = fsig(a);
  }
}
}  // namespace

extern "C" void kernel_launch(void* const* d_in, const int* in_sizes, int n_in,
                              void* d_out, int out_size, void* d_ws,
                              size_t ws_size, hipStream_t stream) {
  const float* x    = (const float*)d_in[0];
  const float* W_ih = (const float*)d_in[1];
  const float* W_hh = (const float*)d_in[2];
  const float* b_ih = (const float*)d_in[3];
  const float* b_hh = (const float*)d_in[4];
  const float* fc_w = (const float*)d_in[5];
  const float* fc_b = (const float*)d_in[6];
  float* out = (float*)d_out;

  const int B = in_sizes[0] / (T_LEN * 8);  // 2048
  lstm_dual<<<dim3(B / R), dim3(256), 0, stream>>>(x, W_ih, W_hh, b_ih, b_hh,
                                                   fc_w, fc_b, out);
}

// Round 9
// 593.467 us; speedup vs baseline: 1.0596x; 1.0596x over previous
//
#include <hip/hip_runtime.h>

// LSTM (B=2048, T=1024, I=8, H=64) + sigmoid(FC), bf16 MFMA.
// Round 9: x-projection hoisted into a per-4-steps pre-pass writing a
// WAVE-PRIVATE xg slab (producer == consumer wave, so no barrier and no
// cross-wave layout constraints — fixes r7's conflict blowup).
// In-loop: K=64 (h only), 2-deep MFMA chain, acc C-INITIALIZED from the slab
// (prefetched one step ahead, off the serial chain). One barrier per step.
// R=4 rows/block -> 512 blocks = 2 blocks/CU; gate-strided M-tiles (wave wv
// owns tiles {4g+wv} -> acc[g] = gate-type g of jh=16wv+4g4+rsel); 1-elem
// in-register activation via hoisted cndmask tree. h double-buffered, HP=72.

namespace {
constexpr int T_LEN = 1024;
constexpr int R     = 4;     // batch rows per block
constexpr int TSX   = 32;    // x staging chunk (timesteps)
constexpr int HP    = 72;    // h row stride (shorts)
// xg slab strides (dwords): [wv][g][g4][col(16)+pad][4]
constexpr int G4S = 68;      // 16 cols * 4 dw + 4 pad  (16B-aligned)
constexpr int GS  = 4 * G4S; // 272
constexpr int WVS = 4 * GS;  // 1088

typedef __attribute__((ext_vector_type(8))) short  short8v;
typedef __attribute__((ext_vector_type(4))) float  float4v;
typedef unsigned short u16;
typedef unsigned int   u32;
typedef unsigned long long u64;

__device__ __forceinline__ float fsig(float x) {
  return __builtin_amdgcn_rcpf(1.f + __expf(-x));
}
__device__ __forceinline__ float ftanh(float x) {
  return 1.f - 2.f * __builtin_amdgcn_rcpf(__expf(2.f * x) + 1.f);
}
__device__ __forceinline__ u16 f2bf(float f) {  // RNE
  u32 u = __float_as_uint(f);
  u32 r = ((u >> 16) & 1u) + 0x7fffu;
  return (u16)((u + r) >> 16);
}

__global__ __launch_bounds__(256, 2) void lstm_hoist(
    const float* __restrict__ x,     // [B, T, 8]
    const float* __restrict__ W_ih,  // [256, 8]
    const float* __restrict__ W_hh,  // [256, 64]
    const float* __restrict__ b_ih,  // [256]
    const float* __restrict__ b_hh,  // [256]
    const float* __restrict__ fc_w,  // [64]
    const float* __restrict__ fc_b,  // [1]
    float* __restrict__ out) {       // [B]
  __shared__ __align__(16) float xg[4 * WVS];        // 17.4 KB, wave-private
  __shared__ __align__(16) u16   x_lds[2][TSX][R][8];// 4 KB  (bf16 x)
  __shared__ __align__(16) u16   h_lds[2][R][HP];    // 1.1 KB
  __shared__ __align__(16) float hf[R][64];          // final h (fp32)

  const int tid  = threadIdx.x;
  const int lane = tid & 63;
  const int wv   = tid >> 6;        // wave 0..3
  const int g4   = lane >> 4;       // MFMA k-quad / C row-quad
  const int nib  = lane & 15;       // MFMA m/n coord
  const int row  = nib & 3;         // batch row (cols duplicate x4)
  const int rsel = nib >> 2;        // which acc reg this thread activates
  const int jh   = 16 * wv + 4 * g4 + rsel;   // owned h index
  const int bBase = blockIdx.x * R;

  // ---- static A fragments: wave wv owns tiles q=4g+wv (g = i,f,g,o) ----
  // apre: K=32 = [W_ih(8)|bias|0...]; ah0 = W_hh[:,0:32]; ah1 = W_hh[:,32:64].
  short8v apre[4], ah0[4], ah1[4];
  for (int g = 0; g < 4; ++g) {
    const int n = 16 * (4 * g + wv) + nib;  // gate row
    short8v fp, f0, f1;
    for (int j = 0; j < 8; ++j) {
      const int k = 8 * g4 + j;
      float vx = 0.f;
      if (k < 8) vx = W_ih[n * 8 + k];
      else if (k == 8) vx = b_ih[n] + b_hh[n];
      fp[j] = (short)f2bf(vx);
      f0[j] = (short)f2bf(W_hh[n * 64 + k]);
      f1[j] = (short)f2bf(W_hh[n * 64 + 32 + k]);
    }
    apre[g] = fp; ah0[g] = f0; ah1[g] = f1;
  }
  short8v bias_frag = {0, 0, 0, 0, 0, 0, 0, 0};
  if (g4 == 1) bias_frag[0] = (short)0x3f80;  // B[k=8][*] = 1.0
  const short8v zero_frag = {0, 0, 0, 0, 0, 0, 0, 0};

  for (int i = tid; i < 2 * R * HP; i += 256) ((u16*)h_lds)[i] = 0;  // h0=0

  // ---- x staging: 1 float4/thread per 32-step chunk ----
  const int stt = tid >> 3, srow = (tid >> 1) & 3, sch = (tid & 1) * 4;
  float4v xr;
  auto stage_load = [&](int chunk) {
    xr = *(const float4v*)&x[(size_t)(bBase + srow) * (T_LEN * 8) +
                             (size_t)(chunk * TSX + stt) * 8 + sch];
  };
  auto stage_write = [&](int buf) {
    union { u64 u; u16 s[4]; } pk;
    pk.s[0] = f2bf(xr[0]); pk.s[1] = f2bf(xr[1]);
    pk.s[2] = f2bf(xr[2]); pk.s[3] = f2bf(xr[3]);
    *(u64*)&x_lds[buf][stt][srow][sch] = pk.u;
  };

  // ---- xg slab addressing (wave-private) ----
  float* const xg_w = &xg[wv * WVS + g4 * G4S + nib * 4];          // store
  const int rdbase  = wv * WVS + g4 * G4S + row * 4;               // + g*GS + lt*16

  // pre-pass for steps 4p..4p+3: N cols = (ttl = nib>>2, row = nib&3)
  auto prepass = [&](int p) {
    const short8v xv =
        *(const short8v*)&x_lds[(p >> 3) & 1][(p & 7) * 4 + (nib >> 2)][nib & 3][0];
    const short8v fxp = (g4 == 0) ? xv : ((g4 == 1) ? bias_frag : zero_frag);
#pragma unroll
    for (int g = 0; g < 4; ++g) {
      const float4v cp = __builtin_amdgcn_mfma_f32_16x16x32_bf16(
          apre[g], fxp, (float4v){0.f, 0.f, 0.f, 0.f}, 0, 0, 0);
      *(float4v*)&xg_w[g * GS] = cp;  // wave-private, no barrier needed
    }
  };

  float4v cinit[4];
  auto cload = [&](int lt) {
#pragma unroll
    for (int g = 0; g < 4; ++g)
      cinit[g] = *(const float4v*)&xg[rdbase + g * GS + lt * 16];
  };

  // ---- prologue ----
  stage_load(0);
  stage_write(0);
  __syncthreads();   // x buf0 + h init visible
  prepass(0);
  cload(0);

  const bool sel1 = (rsel & 1) != 0;
  const bool sel2 = (rsel & 2) != 0;
  float c = 0.f;

  for (int t = 0; t < T_LEN; ++t) {
    const int hb = t & 1;
    if ((t & 31) == 0 && t + TSX < T_LEN) stage_load((t >> 5) + 1);

    // ---- chain: h read -> 2-deep MFMA (C-init = xg) ----
    const short8v fh0 = *(const short8v*)&h_lds[hb][row][8 * g4];
    const short8v fh1 = *(const short8v*)&h_lds[hb][row][32 + 8 * g4];
    float4v acc[4];
#pragma unroll
    for (int g = 0; g < 4; ++g)
      acc[g] = __builtin_amdgcn_mfma_f32_16x16x32_bf16(ah0[g], fh0, cinit[g], 0, 0, 0);
#pragma unroll
    for (int g = 0; g < 4; ++g)
      acc[g] = __builtin_amdgcn_mfma_f32_16x16x32_bf16(ah1[g], fh1, acc[g], 0, 0, 0);

    // ---- select owned element + activation (in-register) ----
    float gv[4];
#pragma unroll
    for (int g = 0; g < 4; ++g) {
      const float x01 = sel1 ? acc[g][1] : acc[g][0];
      const float x23 = sel1 ? acc[g][3] : acc[g][2];
      gv[g] = sel2 ? x23 : x01;
    }
    const float iv = fsig(gv[0]);
    const float fv = fsig(gv[1]);
    const float gg = ftanh(gv[2]);
    const float ov = fsig(gv[3]);
    c = fv * c + iv * gg;
    const float h = ov * ftanh(c);
    h_lds[hb ^ 1][row][jh] = f2bf(h);
    if (t == T_LEN - 1) hf[row][jh] = h;

    // ---- off-chain work: x staging, next pre-pass, cinit prefetch ----
    if ((t & 31) == 28 && t + 4 < T_LEN) stage_write(((t >> 5) + 1) & 1);
    if ((t & 3) == 3 && t + 1 < T_LEN) prepass((t + 1) >> 2);
    if (t + 1 < T_LEN) cload((t + 1) & 3);
    __syncthreads();  // the one barrier per step
  }

  // ---- epilogue: out[b] = sigmoid(hT . fc_w + fc_b) ----
  if (tid < R) {
    float a = fc_b[0];
#pragma unroll
    for (int k = 0; k < 64; ++k) a += hf[tid][k] * fc_w[k];
    out[bBase + tid] = fsig(a);
  }
}
}  // namespace

extern "C" void kernel_launch(void* const* d_in, const int* in_sizes, int n_in,
                              void* d_out, int out_size, void* d_ws,
                              size_t ws_size, hipStream_t stream) {
  const float* x    = (const float*)d_in[0];
  const float* W_ih = (const float*)d_in[1];
  const float* W_hh = (const float*)d_in[2];
  const float* b_ih = (const float*)d_in[3];
  const float* b_hh = (const float*)d_in[4];
  const float* fc_w = (const float*)d_in[5];
  const float* fc_b = (const float*)d_in[6];
  float* out = (float*)d_out;

  const int B = in_sizes[0] / (T_LEN * 8);  // 2048
  lstm_hoist<<<dim3(B / R), dim3(256), 0, stream>>>(x, W_ih, W_hh, b_ih, b_hh,
                                                    fc_w, fc_b, out);
}